// Round 14
// baseline (85.894 us; speedup 1.0000x reference)
//
#include <hip/hip_runtime.h>
#include <math.h>

#define NFEAT 256
#define NROWS 65536
#define PCOUNT 4194304
#define PBLK 64                      // param-reduce blocks appended to pass1 grid
#define CH2 512                      // pass2 fallback chunks
#define RGRP 16                      // reduce_S c-groups
#define F_EPS 5.9604645e-07f         // float32 eps * 5
#define F_LN2 0.69314718056f
#define DELTA_MAX 0.45f              // poly-validity gate on |0.1*rp|

#define FAST_LOG2(v) __builtin_log2f(v)   // v_log_f32
#define FAST_EXP2(v) __builtin_exp2f(v)   // v_exp_f32

constexpr double D_HALF_LOG2_2PIE = 0.5 * 2.8378770664093453 / 0.6931471805599453;
constexpr double D_LAMBDA_BITS = 13.287712379549449; // 2*log2(100)

__device__ inline double wave_reduce_add(double v) {
  for (int o = 32; o > 0; o >>= 1) v += __shfl_down(v, o, 64);
  return v;
}

// ---------------------------------------------------------------------------
// Pass 1: 256-thread blocks, thread t = feature t; block c owns rows
// [c*rpt,(c+1)*rpt). NEW: x tile staged into LDS via coalesced float4 loads
// (16B/lane) -- r7..r13 all read 4B/lane straight from global and were
// load-latency-bound (~1 TB/s effective, dur invariant to instruction mix).
// Compute then reads LDS (2 lanes/bank = conflict-free, ~30cy).
// Poly path (2 trans/elem): exp2(a_j*u) = B * exp(w), w = d_j*q, exp(w) by
// 5th-order Horner (exact to f32 for |w|<=0.86; gated by DELTA_MAX).
// j=0 specialized: d=0 -> E=B.
// Partials: P1[(c*14+k)*NFEAT+f]; k 0..5 sum_y, 6..11 sum_y2,
// 12 sum_u2(pos), 13 sum_u2(all); u2 = log2(1+|x|).
// Blocks >= CHv: parameter tensor reduction (overlapped, memory-bound).
// ---------------------------------------------------------------------------
__global__ __launch_bounds__(256, 4) void k_pass1(
    const float* __restrict__ x, const float* __restrict__ lam1,
    const float* __restrict__ lam2, const float* __restrict__ rp,
    const float* __restrict__ params, float* __restrict__ P1,
    double* __restrict__ pSums, int CHv, int rpt)
{
  const int c = blockIdx.x;
  const int t = threadIdx.x;

  if (c >= CHv) {
    // ---- parameter tensor partial reduction ----
    __shared__ double lred[2][4];
    const int b = c - CHv;
    const float4* p4 = (const float4*)params;
    double s = 0.0, q = 0.0;
    for (int i = b * 256 + t; i < PCOUNT / 4; i += PBLK * 256) {
      float4 v = p4[i];
      s += (double)v.x + (double)v.y + (double)v.z + (double)v.w;
      q += (double)v.x * v.x + (double)v.y * v.y
         + (double)v.z * v.z + (double)v.w * v.w;
    }
    s = wave_reduce_add(s); q = wave_reduce_add(q);
    const int w = t >> 6;
    if ((t & 63) == 0) { lred[0][w] = s; lred[1][w] = q; }
    __syncthreads();
    if (t == 0) {
      atomicAdd(&pSums[0], lred[0][0] + lred[0][1] + lred[0][2] + lred[0][3]);
      atomicAdd(&pSums[1], lred[1][0] + lred[1][1] + lred[1][2] + lred[1][3]);
    }
    return;
  }

  __shared__ float tile[32 * NFEAT];   // 32 KB (rpt <= 32)
  __shared__ int bad;
  if (t == 0) bad = 0;

  // ---- stage tile: coalesced float4 ----
  {
    const float4* src4 = (const float4*)(x + (size_t)c * rpt * NFEAT);
    float4* t4 = (float4*)tile;
    const int n4 = rpt * (NFEAT / 4);        // rpt*64 <= 2048
    for (int idx = t; idx < n4; idx += 256)
      t4[idx] = src4[idx];
  }

  const float L1 = lam1[t], L2 = lam2[t];
  const float An = 2.0f - L2;          // negative-branch center
  float d_p[6], d_n[6], s_p[6], s_n[6];
  bool b = false;
#pragma unroll
  for (int j = 0; j < 6; ++j) {
    float dp = (j == 0) ? 0.0f : 0.1f * rp[t * 10 + 2 * (j - 1)];
    float dn = (j == 0) ? 0.0f : -0.1f * rp[t * 10 + 2 * (j - 1) + 1];
    d_p[j] = dp;  d_n[j] = dn;
    float a1 = L1 + dp;                // l1_j
    float a2 = An + dn;                // 2 - l2_j
    s_p[j] = 1.0f / a1;
    s_n[j] = -1.0f / a2;
    b = b || (fabsf(a1) < F_EPS) || (fabsf(a2) < F_EPS)
          || (fabsf(dp) > DELTA_MAX) || (fabsf(dn) > DELTA_MAX);
  }
  if (b) bad = 1;  // benign same-value race
  __syncthreads();  // tile staged + bad final

  float as[6], aq[6];
#pragma unroll
  for (int j = 0; j < 6; ++j) { as[j] = 0.f; aq[j] = 0.f; }
  float u2p = 0.f, u2a = 0.f;

  if (bad == 0) {
    // ---- poly path: 1 log + 1 exp per element, fed from LDS ----
#pragma unroll 4
    for (int i = 0; i < rpt; ++i) {
      const float v = tile[i * NFEAT + t];
      const bool pos = v >= 0.0f;
      const float u = FAST_LOG2(1.0f + fabsf(v));
      u2a += u;
      u2p += pos ? u : 0.0f;
      const float q = u * F_LN2;
      const float B = FAST_EXP2((pos ? L1 : An) * u);
      // j = 0: d == 0, E == B
      {
        const float s0 = pos ? s_p[0] : s_n[0];
        const float y = fmaf(s0, B, -s0);
        as[0] += y;
        aq[0] = fmaf(y, y, aq[0]);
      }
#pragma unroll
      for (int j = 1; j < 6; ++j) {
        const float d = pos ? d_p[j] : d_n[j];
        const float s = pos ? s_p[j] : s_n[j];
        const float w = d * q;
        float P = fmaf(w, 0.0083333333f, 0.0416666667f);
        P = fmaf(w, P, 0.1666666667f);
        P = fmaf(w, P, 0.5f);
        P = fmaf(w, P, 1.0f);
        P = fmaf(w, P, 1.0f);            // exp(w), 5th order
        const float E = B * P;           // exp2(a_j * u)
        const float y = fmaf(s, E, -s);  // s*(E-1)
        as[j] += y;
        aq[j] = fmaf(y, y, aq[j]);
      }
    }
  } else {
    // ---- exact general path (lambda special cases / large delta) ----
    float ga_p[6], ga_n[6], gs_p[6], gs_n[6], gt_p[6], gt_n[6];
#pragma unroll
    for (int j = 0; j < 6; ++j) {
      float a1 = L1 + d_p[j];
      float a2 = An + d_n[j];
      bool z1 = fabsf(a1) < F_EPS;
      bool z2 = fabsf(a2) < F_EPS;
      ga_p[j] = z1 ? 0.0f : a1;
      gs_p[j] = z1 ? 0.0f : 1.0f / a1;
      gt_p[j] = z1 ? F_LN2 : 0.0f;
      ga_n[j] = z2 ? 0.0f : a2;
      gs_n[j] = z2 ? 0.0f : -1.0f / a2;
      gt_n[j] = z2 ? -F_LN2 : 0.0f;
    }
    for (int i = 0; i < rpt; ++i) {
      float v = tile[i * NFEAT + t];
      bool pos = v >= 0.0f;
      float u2 = FAST_LOG2(1.0f + fabsf(v));
      u2a += u2;
      u2p += pos ? u2 : 0.0f;
#pragma unroll
      for (int j = 0; j < 6; ++j) {
        float a  = pos ? ga_p[j] : ga_n[j];
        float s  = pos ? gs_p[j] : gs_n[j];
        float tt = pos ? gt_p[j] : gt_n[j];
        float e = FAST_EXP2(a * u2);
        float y = fmaf(tt, u2, fmaf(s, e, -s));
        as[j] += y;
        aq[j] = fmaf(y, y, aq[j]);
      }
    }
  }

#pragma unroll
  for (int j = 0; j < 6; ++j) {
    P1[((size_t)c * 14 + j) * NFEAT + t]     = as[j];
    P1[((size_t)c * 14 + 6 + j) * NFEAT + t] = aq[j];
  }
  P1[((size_t)c * 14 + 12) * NFEAT + t] = u2p;
  P1[((size_t)c * 14 + 13) * NFEAT + t] = u2a;
}

// Stage A reduce: block (k, cg): S2[(k*RGRP+cg)*NFEAT+f] = sum over c-subrange.
__global__ __launch_bounds__(256) void k_reduce_S(
    const float* __restrict__ P1, double* __restrict__ S2, int CHv)
{
  const int k = blockIdx.x / RGRP;
  const int cg = blockIdx.x % RGRP;
  const int f = threadIdx.x;
  const int per = CHv / RGRP;
  const int c0 = cg * per;
  double a0 = 0.0, a1 = 0.0, a2 = 0.0, a3 = 0.0;
  for (int c = c0; c < c0 + per; c += 4) {
    a0 += (double)P1[((size_t)(c + 0) * 14 + k) * NFEAT + f];
    a1 += (double)P1[((size_t)(c + 1) * 14 + k) * NFEAT + f];
    a2 += (double)P1[((size_t)(c + 2) * 14 + k) * NFEAT + f];
    a3 += (double)P1[((size_t)(c + 3) * 14 + k) * NFEAT + f];
  }
  S2[((size_t)k * RGRP + cg) * NFEAT + f] = (a0 + a1) + (a2 + a3);
}

// One thread per feature: 6 scores in f64, min, tie-average.
__global__ __launch_bounds__(256) void k_pick(
    const double* __restrict__ S2, const float* __restrict__ lam1,
    const float* __restrict__ lam2, const float* __restrict__ rp,
    float* __restrict__ bestL, int* __restrict__ tied,
    double* __restrict__ bitsF, int* __restrict__ anyTied)
{
  const int f = threadIdx.x;
  if (f == 0) *anyTied = 0;
  double s[14];
#pragma unroll
  for (int k = 0; k < 14; ++k) {
    double a = 0.0;
#pragma unroll
    for (int cg = 0; cg < RGRP; ++cg)
      a += S2[((size_t)k * RGRP + cg) * NFEAT + f];
    s[k] = a;
  }
  const double n = (double)NROWS;
  const double sup = s[12];
  const double sun = s[13] - s[12];
  const float L1 = lam1[f], L2 = lam2[f];
  double scores[6], al1[6], al2[6];
#pragma unroll
  for (int j = 0; j < 6; ++j) {
    float l1 = (j == 0) ? L1 : L1 + 0.1f * rp[f * 10 + 2 * (j - 1)];
    float l2 = (j == 0) ? L2 : L2 + 0.1f * rp[f * 10 + 2 * (j - 1) + 1];
    al1[j] = (double)l1; al2[j] = (double)l2;
    bool z1 = fabsf(l1) < F_EPS;
    bool z2 = fabsf(l2 - 2.0f) < F_EPS;
    double ccp = z1 ? -1.0 : (double)l1 - 1.0;
    double ccn = z2 ? -1.0 : 1.0 - (double)l2;
    double ljb = ccp * sup + ccn * sun;
    double mean = s[j] / n;
    double var = s[6 + j] / n - mean * mean;
    var = var > 1e-12 ? var : 1e-12;
    scores[j] = n * (D_HALF_LOG2_2PIE + 0.5 * log2(var)) + ljb + D_LAMBDA_BITS;
  }
  double mn = scores[0];
#pragma unroll
  for (int j = 1; j < 6; ++j) mn = scores[j] < mn ? scores[j] : mn;
  double wsum = 0.0, b1 = 0.0, b2 = 0.0;
#pragma unroll
  for (int j = 0; j < 6; ++j) {
    double w = (scores[j] == mn) ? 1.0 : 0.0;
    wsum += w; b1 += w * al1[j]; b2 += w * al2[j];
  }
  bestL[2 * f]     = (float)(b1 / wsum);
  bestL[2 * f + 1] = (float)(b2 / wsum);
  const int isTied = (wsum > 1.5) ? 1 : 0;
  tied[f] = isTied;
  if (isTied) atomicOr(anyTied, 1);
  bitsF[f] = mn;   // unique min: identical to re-evaluating at best lambda
}

// Fallback pass 2 (only if some feature tied: averaged lambda is new).
__global__ __launch_bounds__(256) void k_pass2(
    const float* __restrict__ x, const float* __restrict__ bestL,
    const int* __restrict__ anyTied, float* __restrict__ P2)
{
  if (*anyTied == 0) return;
  const int t = threadIdx.x;
  const int c = blockIdx.x;
  const int rpt = NROWS / CH2;   // 128
  const float l1 = bestL[2 * t], l2 = bestL[2 * t + 1];
  const bool z1 = fabsf(l1) < F_EPS;
  const bool z2 = fabsf(l2 - 2.0f) < F_EPS;
  const float tm = 2.0f - l2;
  const float a_p = z1 ? 0.f : l1,  s_pv = z1 ? 0.f : 1.f / l1,  t_pv = z1 ? F_LN2 : 0.f;
  const float a_n = z2 ? 0.f : tm,  s_nv = z2 ? 0.f : -1.f / tm, t_nv = z2 ? -F_LN2 : 0.f;

  float sy = 0.f, sq = 0.f;
  const float* xp = x + (size_t)c * rpt * NFEAT + t;
  for (int i = 0; i < rpt; ++i) {
    float v = xp[(size_t)i * NFEAT];
    bool pos = v >= 0.0f;
    float u2 = FAST_LOG2(1.0f + fabsf(v));
    float a  = pos ? a_p : a_n;
    float s  = pos ? s_pv : s_nv;
    float tt = pos ? t_pv : t_nv;
    float e = FAST_EXP2(a * u2);
    float y = fmaf(tt, u2, fmaf(s, e, -s));
    sy += y;
    sq = fmaf(y, y, sq);
  }
  P2[((size_t)c * 2 + 0) * NFEAT + t] = sy;
  P2[((size_t)c * 2 + 1) * NFEAT + t] = sq;
}

__global__ __launch_bounds__(64) void k_featbits(
    const float* __restrict__ P1, const float* __restrict__ P2,
    const float* __restrict__ bestL, const int* __restrict__ tied,
    double* __restrict__ bitsF, int CHv)
{
  const int f = blockIdx.x;
  if (!tied[f]) return;
  const int lane = threadIdx.x;
  double s0 = 0.0, s1 = 0.0, sup = 0.0, sua = 0.0;
  for (int c = lane; c < CH2; c += 64) {
    s0 += (double)P2[((size_t)c * 2 + 0) * NFEAT + f];
    s1 += (double)P2[((size_t)c * 2 + 1) * NFEAT + f];
  }
  for (int c = lane; c < CHv; c += 64) {
    sup += (double)P1[((size_t)c * 14 + 12) * NFEAT + f];
    sua += (double)P1[((size_t)c * 14 + 13) * NFEAT + f];
  }
  s0 = wave_reduce_add(s0); s1 = wave_reduce_add(s1);
  sup = wave_reduce_add(sup); sua = wave_reduce_add(sua);
  if (lane == 0) {
    const float l1 = bestL[2 * f], l2 = bestL[2 * f + 1];
    bool z1 = fabsf(l1) < F_EPS;
    bool z2 = fabsf(l2 - 2.0f) < F_EPS;
    double ccp = z1 ? -1.0 : (double)l1 - 1.0;
    double ccn = z2 ? -1.0 : 1.0 - (double)l2;
    double ljb = ccp * sup + ccn * (sua - sup);
    const double n = (double)NROWS;
    double mean = s0 / n;
    double var = s1 / n - mean * mean;
    var = var > 1e-12 ? var : 1e-12;
    bitsF[f] = n * (D_HALF_LOG2_2PIE + 0.5 * log2(var)) + ljb + D_LAMBDA_BITS;
  }
}

__global__ __launch_bounds__(256) void k_final(
    const double* __restrict__ bitsF, const double* __restrict__ pSums,
    float* __restrict__ out)
{
  __shared__ double l[4];
  double s = bitsF[threadIdx.x];
  s = wave_reduce_add(s);
  int w = threadIdx.x >> 6;
  if ((threadIdx.x & 63) == 0) l[w] = s;
  __syncthreads();
  if (threadIdx.x == 0) {
    double data = l[0] + l[1] + l[2] + l[3];
    const double n = (double)PCOUNT;
    double mean = pSums[0] / n;
    double var = pSums[1] / n - mean * mean;
    var = var > 1e-12 ? var : 1e-12;
    double model = n * (D_HALF_LOG2_2PIE + 0.5 * log2(var)) + D_LAMBDA_BITS;
    out[0] = (float)(data + model);
  }
}

extern "C" void kernel_launch(void* const* d_in, const int* in_sizes, int n_in,
                              void* d_out, int out_size, void* d_ws, size_t ws_size,
                              hipStream_t stream)
{
  const float* x      = (const float*)d_in[0];
  const float* lam1   = (const float*)d_in[1];
  const float* lam2   = (const float*)d_in[2];
  const float* rp     = (const float*)d_in[3];
  const float* params = (const float*)d_in[4];

  char* ws = (char*)d_ws;
  double* pSums  = (double*)ws;                 // 16 B   -> 16
  float*  bestL  = (float*)(ws + 16);           // 2048   -> 2064
  double* bitsF  = (double*)(ws + 2064);        // 2048   -> 4112
  int*    tied   = (int*)(ws + 4112);           // 1024   -> 5136
  int*    anyT   = (int*)(ws + 5136);           // 4      -> pad 5152
  double* S2     = (double*)(ws + 5152);        // 14*16*256*8 = 458752 -> 463904
  float*  P1     = (float*)(ws + 463904);

  // adaptive chunk count: CH=2048 -> rpt=32 (32KB LDS tile)
  int CHv = 2048;
  while (CHv > 256) {
    size_t need = 463904 + (size_t)CHv * 14 * NFEAT * 4
                         + (size_t)CH2 * 2 * NFEAT * 4;
    if (need <= ws_size) break;
    CHv >>= 1;
  }
  float* P2 = (float*)(ws + 463904 + (size_t)CHv * 14 * NFEAT * 4);
  int rpt = NROWS / CHv;   // 32 at CHv=2048 (tile sized for rpt<=32)

  (void)hipMemsetAsync(pSums, 0, 16, stream);
  k_pass1<<<CHv + PBLK, 256, 0, stream>>>(x, lam1, lam2, rp, params, P1,
                                          pSums, CHv, rpt);
  k_reduce_S<<<14 * RGRP, 256, 0, stream>>>(P1, S2, CHv);
  k_pick<<<1, 256, 0, stream>>>(S2, lam1, lam2, rp, bestL, tied, bitsF, anyT);
  k_pass2<<<CH2, 256, 0, stream>>>(x, bestL, anyT, P2);
  k_featbits<<<NFEAT, 64, 0, stream>>>(P1, P2, bestL, tied, bitsF, CHv);
  k_final<<<1, 256, 0, stream>>>(bitsF, pSums, (float*)d_out);
}

// Round 16
// 69.138 us; speedup vs baseline: 1.2424x; 1.2424x over previous
//
#include <hip/hip_runtime.h>
#include <math.h>

#define NFEAT 256
#define NROWS 65536
#define PCOUNT 4194304
#define PBLK 64                      // param-reduce blocks appended to pass1 grid
#define CH2 512                      // pass2 fallback chunks
#define RGRP 16                      // reduce_S c-groups
#define NSLOT 28                     // P1 slots per chunk per feature
#define F_EPS 5.9604645e-07f         // float32 eps * 5
#define F_LN2 0.69314718056f
#define DELTA_MAX 0.45f              // poly-validity gate on |0.1*rp|

#define FAST_LOG2(v) __builtin_log2f(v)   // v_log_f32
#define FAST_EXP2(v) __builtin_exp2f(v)   // v_exp_f32

constexpr double D_HALF_LOG2_2PIE = 0.5 * 2.8378770664093453 / 0.6931471805599453;
constexpr double D_LAMBDA_BITS = 13.287712379549449; // 2*log2(100)

__device__ inline double wave_reduce_add(double v) {
  for (int o = 32; o > 0; o >>= 1) v += __shfl_down(v, o, 64);
  return v;
}

// sum_k d^k/k! * m[k], k=0..5 (Horner)
__device__ inline double horner_exp(const double* m, double d) {
  double p = m[5] * (1.0 / 120.0);
  p = p * d + m[4] * (1.0 / 24.0);
  p = p * d + m[3] * (1.0 / 6.0);
  p = p * d + m[2] * 0.5;
  p = p * d + m[1];
  p = p * d + m[0];
  return p;
}

// ---------------------------------------------------------------------------
// Pass 1 (moment form): per element accumulate ONLY proposal-independent
// moments: M_k = sum B*q^k, M2_k = sum B^2*q^k (k=0..5, pos/neg separately),
// B = exp2(center*u), q = u*ln2, u = log2(1+|x|).  ~44 VALU + 2 trans/elem
// vs ~72+2 for the per-proposal poly (r12-r14: VALUBusy*dur const ~30us).
// Per-proposal reconstruction happens per-FEATURE in f64 in k_pick:
//   sumE (a=center+d)  = sum_k d^k/k!    * M_k
//   sumE2(a=center+d)  = sum_k (2d)^k/k! * M2_k
//   sum_y  = sp*(sumEp-npos) + sn*(sumEn-nneg)
//   sum_y2 = sp^2*(sumEp2-2*sumEp+npos) + sn^2*(sumEn2-2*sumEn+nneg)
// Identical Taylor truncation to r13 (absmax 0.0 there).
// Slots: 0..5 Mp, 6..11 Mp2, 12..17 Mn, 18..23 Mn2, 24 u2p, 25 u2a,
// 26 npos, 27 flag (0=moments; 1=direct sums from exact general path,
// then slots 0..5 = sum_y, 6..11 = sum_y2).
// 8-deep register prefetch covers global load latency in-thread.
// Blocks >= CHv: parameter tensor reduction (overlapped, memory-bound).
// ---------------------------------------------------------------------------
__global__ __launch_bounds__(256, 4) void k_pass1(
    const float* __restrict__ x, const float* __restrict__ lam1,
    const float* __restrict__ lam2, const float* __restrict__ rp,
    const float* __restrict__ params, float* __restrict__ P1,
    double* __restrict__ pSums, int CHv, int rpt)
{
  const int c = blockIdx.x;
  const int t = threadIdx.x;

  if (c >= CHv) {
    // ---- parameter tensor partial reduction ----
    __shared__ double lred[2][4];
    const int b = c - CHv;
    const float4* p4 = (const float4*)params;
    double s = 0.0, q = 0.0;
    for (int i = b * 256 + t; i < PCOUNT / 4; i += PBLK * 256) {
      float4 v = p4[i];
      s += (double)v.x + (double)v.y + (double)v.z + (double)v.w;
      q += (double)v.x * v.x + (double)v.y * v.y
         + (double)v.z * v.z + (double)v.w * v.w;
    }
    s = wave_reduce_add(s); q = wave_reduce_add(q);
    const int w = t >> 6;
    if ((t & 63) == 0) { lred[0][w] = s; lred[1][w] = q; }
    __syncthreads();
    if (t == 0) {
      atomicAdd(&pSums[0], lred[0][0] + lred[0][1] + lred[0][2] + lred[0][3]);
      atomicAdd(&pSums[1], lred[1][0] + lred[1][1] + lred[1][2] + lred[1][3]);
    }
    return;
  }

  __shared__ int bad;
  if (t == 0) bad = 0;
  __syncthreads();

  const float L1 = lam1[t], L2 = lam2[t];
  const float An = 2.0f - L2;          // negative-branch center
  {
    bool b = (fabsf(L1) < F_EPS) || (fabsf(An) < F_EPS);
#pragma unroll
    for (int j = 1; j < 6; ++j) {
      float dp = 0.1f * rp[t * 10 + 2 * (j - 1)];
      float dn = -0.1f * rp[t * 10 + 2 * (j - 1) + 1];
      b = b || (fabsf(L1 + dp) < F_EPS) || (fabsf(An + dn) < F_EPS)
            || (fabsf(dp) > DELTA_MAX) || (fabsf(dn) > DELTA_MAX);
    }
    if (b) bad = 1;  // benign same-value race
  }
  __syncthreads();

  const float* xp = x + (size_t)c * rpt * NFEAT + t;
  float out[NSLOT];

  if (bad == 0) {
    // ---- moment path ----
    float Mp[6], Mp2[6], Mn[6], Mn2[6];
#pragma unroll
    for (int k = 0; k < 6; ++k) { Mp[k] = 0.f; Mp2[k] = 0.f; Mn[k] = 0.f; Mn2[k] = 0.f; }
    float u2p = 0.f, u2a = 0.f, npos = 0.f;

    float vb[8], vn[8];
#pragma unroll
    for (int r = 0; r < 8; ++r) vb[r] = xp[(size_t)r * NFEAT];
    for (int g = 0; g < rpt; g += 8) {
      const bool more = (g + 8 < rpt);
      if (more) {
#pragma unroll
        for (int r = 0; r < 8; ++r) vn[r] = xp[(size_t)(g + 8 + r) * NFEAT];
      }
#pragma unroll
      for (int r = 0; r < 8; ++r) {
        const float v = vb[r];
        const bool pos = v >= 0.0f;
        const float u = FAST_LOG2(1.0f + fabsf(v));
        u2a += u;
        u2p += pos ? u : 0.0f;
        npos += pos ? 1.0f : 0.0f;
        const float q = u * F_LN2;
        const float B = FAST_EXP2((pos ? L1 : An) * u);
        const float B2 = B * B;
        const float Bp = pos ? B : 0.0f;
        const float Bn = B - Bp;
        const float Cp = pos ? B2 : 0.0f;
        const float Cn = B2 - Cp;
        Mp[0] += Bp; Mp2[0] += Cp; Mn[0] += Bn; Mn2[0] += Cn;
        float qk = q;
        Mp[1] = fmaf(Bp, qk, Mp[1]); Mp2[1] = fmaf(Cp, qk, Mp2[1]);
        Mn[1] = fmaf(Bn, qk, Mn[1]); Mn2[1] = fmaf(Cn, qk, Mn2[1]);
#pragma unroll
        for (int k = 2; k < 6; ++k) {
          qk *= q;
          Mp[k] = fmaf(Bp, qk, Mp[k]); Mp2[k] = fmaf(Cp, qk, Mp2[k]);
          Mn[k] = fmaf(Bn, qk, Mn[k]); Mn2[k] = fmaf(Cn, qk, Mn2[k]);
        }
      }
      if (more) {
#pragma unroll
        for (int r = 0; r < 8; ++r) vb[r] = vn[r];
      }
    }
#pragma unroll
    for (int k = 0; k < 6; ++k) {
      out[k]      = Mp[k];
      out[6 + k]  = Mp2[k];
      out[12 + k] = Mn[k];
      out[18 + k] = Mn2[k];
    }
    out[24] = u2p; out[25] = u2a; out[26] = npos; out[27] = 0.0f;
  } else {
    // ---- exact general path: direct sums (flag=1) ----
    float ga_p[6], ga_n[6], gs_p[6], gs_n[6], gt_p[6], gt_n[6];
#pragma unroll
    for (int j = 0; j < 6; ++j) {
      float dp = (j == 0) ? 0.0f : 0.1f * rp[t * 10 + 2 * (j - 1)];
      float dn = (j == 0) ? 0.0f : -0.1f * rp[t * 10 + 2 * (j - 1) + 1];
      float a1 = L1 + dp;
      float a2 = An + dn;
      bool z1 = fabsf(a1) < F_EPS;
      bool z2 = fabsf(a2) < F_EPS;
      ga_p[j] = z1 ? 0.0f : a1;
      gs_p[j] = z1 ? 0.0f : 1.0f / a1;
      gt_p[j] = z1 ? F_LN2 : 0.0f;
      ga_n[j] = z2 ? 0.0f : a2;
      gs_n[j] = z2 ? 0.0f : -1.0f / a2;
      gt_n[j] = z2 ? -F_LN2 : 0.0f;
    }
    float as[6], aq[6];
#pragma unroll
    for (int j = 0; j < 6; ++j) { as[j] = 0.f; aq[j] = 0.f; }
    float u2p = 0.f, u2a = 0.f;
    for (int i = 0; i < rpt; ++i) {
      float v = xp[(size_t)i * NFEAT];
      bool pos = v >= 0.0f;
      float u2 = FAST_LOG2(1.0f + fabsf(v));
      u2a += u2;
      u2p += pos ? u2 : 0.0f;
#pragma unroll
      for (int j = 0; j < 6; ++j) {
        float a  = pos ? ga_p[j] : ga_n[j];
        float s  = pos ? gs_p[j] : gs_n[j];
        float tt = pos ? gt_p[j] : gt_n[j];
        float e = FAST_EXP2(a * u2);
        float y = fmaf(tt, u2, fmaf(s, e, -s));
        as[j] += y;
        aq[j] = fmaf(y, y, aq[j]);
      }
    }
#pragma unroll
    for (int k = 0; k < NSLOT; ++k) out[k] = 0.0f;
#pragma unroll
    for (int j = 0; j < 6; ++j) { out[j] = as[j]; out[6 + j] = aq[j]; }
    out[24] = u2p; out[25] = u2a; out[26] = 0.0f; out[27] = 1.0f;
  }

#pragma unroll
  for (int k = 0; k < NSLOT; ++k)
    P1[((size_t)c * NSLOT + k) * NFEAT + t] = out[k];
}

// Stage A reduce: block (k, cg): S2[(k*RGRP+cg)*NFEAT+f] = sum over c-subrange.
__global__ __launch_bounds__(256) void k_reduce_S(
    const float* __restrict__ P1, double* __restrict__ S2, int CHv)
{
  const int k = blockIdx.x / RGRP;
  const int cg = blockIdx.x % RGRP;
  const int f = threadIdx.x;
  const int per = CHv / RGRP;
  const int c0 = cg * per;
  double a0 = 0.0, a1 = 0.0, a2 = 0.0, a3 = 0.0;
  for (int c = c0; c < c0 + per; c += 4) {
    a0 += (double)P1[((size_t)(c + 0) * NSLOT + k) * NFEAT + f];
    a1 += (double)P1[((size_t)(c + 1) * NSLOT + k) * NFEAT + f];
    a2 += (double)P1[((size_t)(c + 2) * NSLOT + k) * NFEAT + f];
    a3 += (double)P1[((size_t)(c + 3) * NSLOT + k) * NFEAT + f];
  }
  S2[((size_t)k * RGRP + cg) * NFEAT + f] = (a0 + a1) + (a2 + a3);
}

// One thread per feature: reconstruct 6 scores in f64, min, tie-average.
__global__ __launch_bounds__(256) void k_pick(
    const double* __restrict__ S2, const float* __restrict__ lam1,
    const float* __restrict__ lam2, const float* __restrict__ rp,
    float* __restrict__ bestL, int* __restrict__ tied,
    double* __restrict__ bitsF, int* __restrict__ anyTied)
{
  const int f = threadIdx.x;
  if (f == 0) *anyTied = 0;
  double s[NSLOT];
#pragma unroll
  for (int k = 0; k < NSLOT; ++k) {
    double a = 0.0;
#pragma unroll
    for (int cg = 0; cg < RGRP; ++cg)
      a += S2[((size_t)k * RGRP + cg) * NFEAT + f];
    s[k] = a;
  }
  const double n = (double)NROWS;
  const bool direct = s[27] > 0.5;
  const double npos = s[26];
  const double nneg = n - npos;
  const double sup = s[24];
  const double sun = s[25] - s[24];
  const float L1 = lam1[f], L2 = lam2[f];
  const double dAn = 2.0 - (double)L2;   // f64 negative-branch center
  double scores[6], al1[6], al2[6];
#pragma unroll
  for (int j = 0; j < 6; ++j) {
    float l1 = (j == 0) ? L1 : L1 + 0.1f * rp[f * 10 + 2 * (j - 1)];
    float l2 = (j == 0) ? L2 : L2 + 0.1f * rp[f * 10 + 2 * (j - 1) + 1];
    al1[j] = (double)l1; al2[j] = (double)l2;
    bool z1 = fabsf(l1) < F_EPS;
    bool z2 = fabsf(l2 - 2.0f) < F_EPS;
    double ccp = z1 ? -1.0 : (double)l1 - 1.0;
    double ccn = z2 ? -1.0 : 1.0 - (double)l2;
    double ljb = ccp * sup + ccn * sun;

    double sum_y, sum_y2;
    if (direct) {
      sum_y  = s[j];
      sum_y2 = s[6 + j];
    } else {
      const double dp  = (double)l1 - (double)L1;          // exact f64 delta
      const double dnn = (2.0 - (double)l2) - dAn;
      const double sp = 1.0 / ((double)L1 + dp);
      const double sn = -1.0 / (dAn + dnn);
      const double Ep  = horner_exp(&s[0],  dp);
      const double Ep2 = horner_exp(&s[6],  2.0 * dp);
      const double En  = horner_exp(&s[12], dnn);
      const double En2 = horner_exp(&s[18], 2.0 * dnn);
      sum_y  = sp * (Ep - npos) + sn * (En - nneg);
      sum_y2 = sp * sp * (Ep2 - 2.0 * Ep + npos)
             + sn * sn * (En2 - 2.0 * En + nneg);
    }
    double mean = sum_y / n;
    double var = sum_y2 / n - mean * mean;
    var = var > 1e-12 ? var : 1e-12;
    scores[j] = n * (D_HALF_LOG2_2PIE + 0.5 * log2(var)) + ljb + D_LAMBDA_BITS;
  }
  double mn = scores[0];
#pragma unroll
  for (int j = 1; j < 6; ++j) mn = scores[j] < mn ? scores[j] : mn;
  double wsum = 0.0, b1 = 0.0, b2 = 0.0;
#pragma unroll
  for (int j = 0; j < 6; ++j) {
    double w = (scores[j] == mn) ? 1.0 : 0.0;
    wsum += w; b1 += w * al1[j]; b2 += w * al2[j];
  }
  bestL[2 * f]     = (float)(b1 / wsum);
  bestL[2 * f + 1] = (float)(b2 / wsum);
  const int isTied = (wsum > 1.5) ? 1 : 0;
  tied[f] = isTied;
  if (isTied) atomicOr(anyTied, 1);
  bitsF[f] = mn;   // unique min: identical to re-evaluating at best lambda
}

// Fallback pass 2 (only if some feature tied: averaged lambda is new).
__global__ __launch_bounds__(256) void k_pass2(
    const float* __restrict__ x, const float* __restrict__ bestL,
    const int* __restrict__ anyTied, float* __restrict__ P2)
{
  if (*anyTied == 0) return;
  const int t = threadIdx.x;
  const int c = blockIdx.x;
  const int rpt = NROWS / CH2;   // 128
  const float l1 = bestL[2 * t], l2 = bestL[2 * t + 1];
  const bool z1 = fabsf(l1) < F_EPS;
  const bool z2 = fabsf(l2 - 2.0f) < F_EPS;
  const float tm = 2.0f - l2;
  const float a_p = z1 ? 0.f : l1,  s_pv = z1 ? 0.f : 1.f / l1,  t_pv = z1 ? F_LN2 : 0.f;
  const float a_n = z2 ? 0.f : tm,  s_nv = z2 ? 0.f : -1.f / tm, t_nv = z2 ? -F_LN2 : 0.f;

  float sy = 0.f, sq = 0.f;
  const float* xp = x + (size_t)c * rpt * NFEAT + t;
  for (int i = 0; i < rpt; ++i) {
    float v = xp[(size_t)i * NFEAT];
    bool pos = v >= 0.0f;
    float u2 = FAST_LOG2(1.0f + fabsf(v));
    float a  = pos ? a_p : a_n;
    float s  = pos ? s_pv : s_nv;
    float tt = pos ? t_pv : t_nv;
    float e = FAST_EXP2(a * u2);
    float y = fmaf(tt, u2, fmaf(s, e, -s));
    sy += y;
    sq = fmaf(y, y, sq);
  }
  P2[((size_t)c * 2 + 0) * NFEAT + t] = sy;
  P2[((size_t)c * 2 + 1) * NFEAT + t] = sq;
}

__global__ __launch_bounds__(64) void k_featbits(
    const float* __restrict__ P1, const float* __restrict__ P2,
    const float* __restrict__ bestL, const int* __restrict__ tied,
    double* __restrict__ bitsF, int CHv)
{
  const int f = blockIdx.x;
  if (!tied[f]) return;
  const int lane = threadIdx.x;
  double s0 = 0.0, s1 = 0.0, sup = 0.0, sua = 0.0;
  for (int c = lane; c < CH2; c += 64) {
    s0 += (double)P2[((size_t)c * 2 + 0) * NFEAT + f];
    s1 += (double)P2[((size_t)c * 2 + 1) * NFEAT + f];
  }
  for (int c = lane; c < CHv; c += 64) {
    sup += (double)P1[((size_t)c * NSLOT + 24) * NFEAT + f];
    sua += (double)P1[((size_t)c * NSLOT + 25) * NFEAT + f];
  }
  s0 = wave_reduce_add(s0); s1 = wave_reduce_add(s1);
  sup = wave_reduce_add(sup); sua = wave_reduce_add(sua);
  if (lane == 0) {
    const float l1 = bestL[2 * f], l2 = bestL[2 * f + 1];
    bool z1 = fabsf(l1) < F_EPS;
    bool z2 = fabsf(l2 - 2.0f) < F_EPS;
    double ccp = z1 ? -1.0 : (double)l1 - 1.0;
    double ccn = z2 ? -1.0 : 1.0 - (double)l2;
    double ljb = ccp * sup + ccn * (sua - sup);
    const double n = (double)NROWS;
    double mean = s0 / n;
    double var = s1 / n - mean * mean;
    var = var > 1e-12 ? var : 1e-12;
    bitsF[f] = n * (D_HALF_LOG2_2PIE + 0.5 * log2(var)) + ljb + D_LAMBDA_BITS;
  }
}

__global__ __launch_bounds__(256) void k_final(
    const double* __restrict__ bitsF, const double* __restrict__ pSums,
    float* __restrict__ out)
{
  __shared__ double l[4];
  double s = bitsF[threadIdx.x];
  s = wave_reduce_add(s);
  int w = threadIdx.x >> 6;
  if ((threadIdx.x & 63) == 0) l[w] = s;
  __syncthreads();
  if (threadIdx.x == 0) {
    double data = l[0] + l[1] + l[2] + l[3];
    const double n = (double)PCOUNT;
    double mean = pSums[0] / n;
    double var = pSums[1] / n - mean * mean;
    var = var > 1e-12 ? var : 1e-12;
    double model = n * (D_HALF_LOG2_2PIE + 0.5 * log2(var)) + D_LAMBDA_BITS;
    out[0] = (float)(data + model);
  }
}

extern "C" void kernel_launch(void* const* d_in, const int* in_sizes, int n_in,
                              void* d_out, int out_size, void* d_ws, size_t ws_size,
                              hipStream_t stream)
{
  const float* x      = (const float*)d_in[0];
  const float* lam1   = (const float*)d_in[1];
  const float* lam2   = (const float*)d_in[2];
  const float* rp     = (const float*)d_in[3];
  const float* params = (const float*)d_in[4];

  char* ws = (char*)d_ws;
  double* pSums  = (double*)ws;                 // 16 B   -> 16
  float*  bestL  = (float*)(ws + 16);           // 2048   -> 2064
  double* bitsF  = (double*)(ws + 2064);        // 2048   -> 4112
  int*    tied   = (int*)(ws + 4112);           // 1024   -> 5136
  int*    anyT   = (int*)(ws + 5136);           // 4      -> pad 5152
  double* S2     = (double*)(ws + 5152);        // 28*16*256*8 = 917504 -> 922656
  float*  P1     = (float*)(ws + 922656);

  // adaptive chunk count (28 f32 slots per chunk per feature)
  int CHv = 1024;
  while (CHv > 128) {
    size_t need = 922656 + (size_t)CHv * NSLOT * NFEAT * 4
                         + (size_t)CH2 * 2 * NFEAT * 4;
    if (need <= ws_size) break;
    CHv >>= 1;
  }
  float* P2 = (float*)(ws + 922656 + (size_t)CHv * NSLOT * NFEAT * 4);
  int rpt = NROWS / CHv;   // 64 at CHv=1024

  (void)hipMemsetAsync(pSums, 0, 16, stream);
  k_pass1<<<CHv + PBLK, 256, 0, stream>>>(x, lam1, lam2, rp, params, P1,
                                          pSums, CHv, rpt);
  k_reduce_S<<<NSLOT * RGRP, 256, 0, stream>>>(P1, S2, CHv);
  k_pick<<<1, 256, 0, stream>>>(S2, lam1, lam2, rp, bestL, tied, bitsF, anyT);
  k_pass2<<<CH2, 256, 0, stream>>>(x, bestL, anyT, P2);
  k_featbits<<<NFEAT, 64, 0, stream>>>(P1, P2, bestL, tied, bitsF, CHv);
  k_final<<<1, 256, 0, stream>>>(bitsF, pSums, (float*)d_out);
}